// Round 8
// baseline (142.882 us; speedup 1.0000x reference)
//
#include <hip/hip_runtime.h>

#define N_FEAT 2048
#define ORDER 8
#define BATCH 8192
#define BLOCK 256
#define ROWS 4                      // batch rows per tile
#define TILES 4                     // sequential tiles per block (pipelined)
#define GRID (BATCH / (ROWS * TILES))   // 512 blocks
#define NTILES (BATCH / ROWS)           // 2048 tiles total

typedef float v4f __attribute__((ext_vector_type(4)));

__device__ __forceinline__ float dot4(v4f a, v4f b) {
    return a.x * b.x + a.y * b.y + a.z * b.z + a.w * b.w;
}

// Prep kernel (1 block): normalize the 8 reflection vectors into ws.
__global__ __launch_bounds__(BLOCK) void prep_kernel(
    const float* __restrict__ v, float* __restrict__ vn) {
    const int tid = threadIdx.x;
    const int lane = tid & 63, wid = tid >> 6;

    v4f a0[ORDER], a1[ORDER];
    #pragma unroll
    for (int i = 0; i < ORDER; ++i) {
        a0[i] = *(const v4f*)(v + (size_t)i * N_FEAT + tid * 4);
        a1[i] = *(const v4f*)(v + (size_t)i * N_FEAT + 1024 + tid * 4);
    }
    float ss[ORDER];
    #pragma unroll
    for (int i = 0; i < ORDER; ++i)
        ss[i] = dot4(a0[i], a0[i]) + dot4(a1[i], a1[i]);
    #pragma unroll
    for (int o = 32; o > 0; o >>= 1)
        #pragma unroll
        for (int i = 0; i < ORDER; ++i) ss[i] += __shfl_down(ss[i], o, 64);

    __shared__ float red[4][ORDER];
    if (lane == 0) {
        #pragma unroll
        for (int i = 0; i < ORDER; ++i) red[wid][i] = ss[i];
    }
    __syncthreads();
    #pragma unroll
    for (int i = 0; i < ORDER; ++i) {
        const float inv = 1.0f / sqrtf(red[0][i] + red[1][i] + red[2][i] + red[3][i]);
        *(v4f*)(vn + (size_t)i * N_FEAT + tid * 4) = a0[i] * inv;
        *(v4f*)(vn + (size_t)i * N_FEAT + 1024 + tid * 4) = a1[i] * inv;
    }
}

// Apply kernel: each block walks TILES=4 tiles of ROWS=4 rows. While tile t
// runs its 8 reflection iterations (HBM-idle phase in prior rounds), tile
// t+1's x loads are already in flight (register prefetch, one set live).
__global__ __launch_bounds__(BLOCK) void orth_apply_kernel(
    const float* __restrict__ x, const float* __restrict__ vn,
    const float* __restrict__ d, const float* __restrict__ bias,
    float* __restrict__ y) {
    const int tid = threadIdx.x;
    const int lane = tid & 63, wid = tid >> 6;
    const int c0 = tid * 4;
    const int c1 = 1024 + tid * 4;

    // Loop-invariant epilogue vectors: load once per block.
    const v4f d0 = *(const v4f*)(d + c0);
    const v4f d1 = *(const v4f*)(d + c1);
    const v4f b0 = *(const v4f*)(bias + c0);
    const v4f b1 = *(const v4f*)(bias + c1);

    __shared__ float red[2][4][ROWS];

    const int tile0 = blockIdx.x * TILES;
    size_t base = (size_t)tile0 * ROWS * N_FEAT;

    v4f z0[ROWS], z1[ROWS];
    #pragma unroll
    for (int r = 0; r < ROWS; ++r) {
        z0[r] = *(const v4f*)(x + base + (size_t)r * N_FEAT + c0);
        z1[r] = *(const v4f*)(x + base + (size_t)r * N_FEAT + c1);
    }

    #pragma unroll 1   // keep rolled: exactly ONE prefetch register set live
    for (int t = 0; t < TILES; ++t) {
        // Prefetch next tile's x (clamped address; result unused on last tile).
        const int ntile = (t + 1 < TILES) ? (tile0 + t + 1) : (NTILES - 1);
        const size_t nbase = (size_t)ntile * ROWS * N_FEAT;
        v4f pf0[ROWS], pf1[ROWS];
        #pragma unroll
        for (int r = 0; r < ROWS; ++r) {
            pf0[r] = *(const v4f*)(x + nbase + (size_t)r * N_FEAT + c0);
            pf1[r] = *(const v4f*)(x + nbase + (size_t)r * N_FEAT + c1);
        }

        // 8 serialized reflections on the current tile.
        #pragma unroll
        for (int i = 0; i < ORDER; ++i) {
            const float* vr = vn + (size_t)i * N_FEAT;
            const v4f a0 = *(const v4f*)(vr + c0);
            const v4f a1 = *(const v4f*)(vr + c1);

            float p[ROWS];
            #pragma unroll
            for (int r = 0; r < ROWS; ++r)
                p[r] = dot4(z0[r], a0) + dot4(z1[r], a1);
            #pragma unroll
            for (int o = 32; o > 0; o >>= 1)
                #pragma unroll
                for (int r = 0; r < ROWS; ++r) p[r] += __shfl_down(p[r], o, 64);

            const int buf = i & 1;
            if (lane == 0) {
                #pragma unroll
                for (int r = 0; r < ROWS; ++r) red[buf][wid][r] = p[r];
            }
            __syncthreads();

            #pragma unroll
            for (int r = 0; r < ROWS; ++r) {
                const float s = -2.0f * (red[buf][0][r] + red[buf][1][r] +
                                         red[buf][2][r] + red[buf][3][r]);
                z0[r] += s * a0;
                z1[r] += s * a1;
            }
        }

        // Epilogue + store current tile.
        #pragma unroll
        for (int r = 0; r < ROWS; ++r) {
            v4f o0 = z0[r] * d0 + b0;
            v4f o1 = z1[r] * d1 + b1;
            __builtin_nontemporal_store(o0, (v4f*)(y + base + (size_t)r * N_FEAT + c0));
            __builtin_nontemporal_store(o1, (v4f*)(y + base + (size_t)r * N_FEAT + c1));
        }

        // Rotate prefetch -> current.
        #pragma unroll
        for (int r = 0; r < ROWS; ++r) { z0[r] = pf0[r]; z1[r] = pf1[r]; }
        base = nbase;
    }
}

extern "C" void kernel_launch(void* const* d_in, const int* in_sizes, int n_in,
                              void* d_out, int out_size, void* d_ws, size_t ws_size,
                              hipStream_t stream) {
    const float* x    = (const float*)d_in[0];  // [8192, 2048]
    const float* v    = (const float*)d_in[1];  // [8, 2048]
    const float* d    = (const float*)d_in[2];  // [2048]
    const float* bias = (const float*)d_in[3];  // [2048]
    float* y  = (float*)d_out;                  // [8192, 2048]
    float* vn = (float*)d_ws;                   // [8, 2048]

    prep_kernel<<<1, BLOCK, 0, stream>>>(v, vn);
    orth_apply_kernel<<<GRID, BLOCK, 0, stream>>>(x, vn, d, bias, y);
}